// Round 1
// baseline (1315.937 us; speedup 1.0000x reference)
//
#include <hip/hip_runtime.h>
#include <math.h>

// ---------------------------------------------------------------------------
// CapsuleNetwork forward, fp32 baseline.
//   K1 conv1:  img[128,1,28,28] -> x[128,256,20,20]  (9x9, s1, relu+bias)
//   K2 pcaps:  x -> partial sums part[4][128][32][36][8]  (9x9, s2, 64-ic chunks)
//   K3 squash: part(+bias) -> u[128,1152,8]
//   K4 routing: u, route_w -> out[128,10,16]  (3 dynamic-routing iters, per-(b,o) block)
// ---------------------------------------------------------------------------

__global__ __launch_bounds__(256) void conv1_kernel(
    const float* __restrict__ img,   // [128][28][28]
    const float* __restrict__ w,     // [256][9][9]
    const float* __restrict__ bias,  // [256]
    float* __restrict__ x)           // [128][256][20][20]
{
    const int ct = blockIdx.x;   // 0..3 (64-channel tile)
    const int b  = blockIdx.y;   // 0..127
    const int t  = threadIdx.x;
    __shared__ float img_s[784];
    __shared__ float w_s[64 * 81];
    for (int idx = t; idx < 784; idx += 256) img_s[idx] = img[b * 784 + idx];
    for (int idx = t; idx < 64 * 81; idx += 256) w_s[idx] = w[ct * 64 * 81 + idx];
    __syncthreads();
    // 64 channels x 20 output rows = 1280 tasks, 5 per thread
    for (int task = t; task < 1280; task += 256) {
        const int cl = task / 20;
        const int oy = task - cl * 20;
        float acc[20];
        const float bv = bias[ct * 64 + cl];
#pragma unroll
        for (int j = 0; j < 20; ++j) acc[j] = bv;
#pragma unroll
        for (int ky = 0; ky < 9; ++ky) {
            float rowv[28];
            const float* r = &img_s[(oy + ky) * 28];
#pragma unroll
            for (int j = 0; j < 28; ++j) rowv[j] = r[j];
#pragma unroll
            for (int kx = 0; kx < 9; ++kx) {
                const float wv = w_s[cl * 81 + ky * 9 + kx];
#pragma unroll
                for (int j = 0; j < 20; ++j) acc[j] += wv * rowv[j + kx];
            }
        }
        float* xp = x + (((size_t)b * 256 + ct * 64 + cl) * 400) + oy * 20;
#pragma unroll
        for (int j = 0; j < 20; ++j) xp[j] = fmaxf(acc[j], 0.f);
    }
}

// Block tile: 128 oc x 36 pos, 64-ic K-chunk. 192 threads: ocg=t&31 (4 oc each),
// oy=t>>5 (full 6-wide output row per thread). w staged transposed w_s[k][oc]
// (row stride 132 for b128-aligned reads).
__global__ __launch_bounds__(192) void pcaps_kernel(
    const float* __restrict__ x,    // [128][256][400]
    const float* __restrict__ w,    // [256][256][81]
    float* __restrict__ part)       // [4][128][32][36][8]
{
    const int b   = blockIdx.x;  // 128
    const int oct = blockIdx.y;  // 2
    const int ict = blockIdx.z;  // 4
    const int t = threadIdx.x;
    __shared__ float w_s[81 * 132];
    __shared__ float x_s[400];
    const int ocg = t & 31;
    const int oy  = t >> 5;      // 0..5
    const int oc4 = ocg * 4;
    float acc[6][4];
#pragma unroll
    for (int p = 0; p < 6; ++p) {
        acc[p][0] = 0.f; acc[p][1] = 0.f; acc[p][2] = 0.f; acc[p][3] = 0.f;
    }
    const float* xb = x + (size_t)b * 102400 + (size_t)ict * 64 * 400;
    const float* wb = w + (size_t)(oct * 128) * 20736 + (size_t)ict * 64 * 81;
    for (int ic = 0; ic < 64; ++ic) {
        for (int idx = t; idx < 400; idx += 192) x_s[idx] = xb[ic * 400 + idx];
        for (int idx = t; idx < 10368; idx += 192) {
            const int oc = idx / 81;
            const int k  = idx - oc * 81;
            w_s[k * 132 + oc] = wb[(size_t)oc * 20736 + ic * 81 + k];
        }
        __syncthreads();
#pragma unroll
        for (int ky = 0; ky < 9; ++ky) {
            float rowv[19];
            const float* xr = &x_s[(2 * oy + ky) * 20];
#pragma unroll
            for (int j = 0; j < 19; ++j) rowv[j] = xr[j];
#pragma unroll
            for (int kx = 0; kx < 9; ++kx) {
                const float4 wv = *(const float4*)&w_s[(ky * 9 + kx) * 132 + oc4];
#pragma unroll
                for (int p = 0; p < 6; ++p) {
                    const float xv = rowv[2 * p + kx];
                    acc[p][0] += xv * wv.x; acc[p][1] += xv * wv.y;
                    acc[p][2] += xv * wv.z; acc[p][3] += xv * wv.w;
                }
            }
        }
        __syncthreads();
    }
    float* pb = part + ((size_t)ict * 128 + b) * 9216;
#pragma unroll
    for (int p = 0; p < 6; ++p) {
        const int pos = oy * 6 + p;
#pragma unroll
        for (int j = 0; j < 4; ++j) {
            const int oc  = oct * 128 + oc4 + j;
            const int cap = oc >> 3;
            const int d   = oc & 7;
            pb[((size_t)cap * 36 + pos) * 8 + d] = acc[p][j];
        }
    }
}

__global__ __launch_bounds__(256) void squash_kernel(
    const float* __restrict__ part,  // [4][128*1152][8]
    const float* __restrict__ bias,  // [256] = [32][8]
    float* __restrict__ u)           // [128*1152][8]
{
    const int idx = blockIdx.x * 256 + threadIdx.x;  // 0..147455
    if (idx >= 128 * 1152) return;
    const int i   = idx % 1152;
    const int cap = i / 36;
    float v[8];
    float n2 = 0.f;
#pragma unroll
    for (int c = 0; c < 8; ++c) {
        float s = bias[cap * 8 + c];
#pragma unroll
        for (int q = 0; q < 4; ++q) s += part[(size_t)q * 1179648 + (size_t)idx * 8 + c];
        v[c] = s;
        n2 += s * s;
    }
    const float sc = sqrtf(n2) / (1.f + n2);
#pragma unroll
    for (int c = 0; c < 8; ++c) u[(size_t)idx * 8 + c] = v[c] * sc;
}

__device__ __forceinline__ float4 uhat4(const float* __restrict__ urow,
                                        const float* __restrict__ wrow)
{
    float ur[8];
    const float4 u0 = *(const float4*)urow;
    const float4 u1 = *(const float4*)(urow + 4);
    ur[0] = u0.x; ur[1] = u0.y; ur[2] = u0.z; ur[3] = u0.w;
    ur[4] = u1.x; ur[5] = u1.y; ur[6] = u1.z; ur[7] = u1.w;
    float4 uh = make_float4(0.f, 0.f, 0.f, 0.f);
#pragma unroll
    for (int c = 0; c < 8; ++c) {
        const float4 wv = *(const float4*)(wrow + c * 16);
        uh.x += ur[c] * wv.x; uh.y += ur[c] * wv.y;
        uh.z += ur[c] * wv.z; uh.w += ur[c] * wv.w;
    }
    return uh;
}

// One block per (b, o): entire 3-iteration routing is local. u_hat recomputed
// on the fly each pass (route_w slice is L2-resident; keeps LDS < 64 KB).
__global__ __launch_bounds__(256) void routing_kernel(
    const float* __restrict__ u,    // [128][1152][8]
    const float* __restrict__ rw,   // [10][1152][8][16]
    float* __restrict__ out)        // [128][10][16]
{
    const int b = blockIdx.x;   // 128 (fastest -> same-o blocks adjacent for L2)
    const int o = blockIdx.y;   // 10
    const int t = threadIdx.x;
    __shared__ float logits[1152];
    __shared__ float ebuf[1152];
    __shared__ float psum[64][17];
    __shared__ float red[8];
    __shared__ float v_s[16];
    const float* ub = u + (size_t)b * 9216;
    const float* wo = rw + (size_t)o * 147456;
    for (int i = t; i < 1152; i += 256) logits[i] = 0.f;
    __syncthreads();
    const int dq = t & 3;
    const int ig = t >> 2;
    const int d4 = dq * 4;
    for (int iter = 1; iter <= 3; ++iter) {
        // softmax over in_caps: max then sum(exp)
        float lmax = -3.0e38f;
        for (int i = t; i < 1152; i += 256) lmax = fmaxf(lmax, logits[i]);
#pragma unroll
        for (int off = 32; off; off >>= 1) lmax = fmaxf(lmax, __shfl_xor(lmax, off, 64));
        if ((t & 63) == 0) red[t >> 6] = lmax;
        __syncthreads();
        const float m = fmaxf(fmaxf(red[0], red[1]), fmaxf(red[2], red[3]));
        float ls = 0.f;
        for (int i = t; i < 1152; i += 256) {
            const float e = expf(logits[i] - m);
            ebuf[i] = e;
            ls += e;
        }
#pragma unroll
        for (int off = 32; off; off >>= 1) ls += __shfl_xor(ls, off, 64);
        if ((t & 63) == 0) red[4 + (t >> 6)] = ls;
        __syncthreads();
        const float sumE = red[4] + red[5] + red[6] + red[7];
        // s[d] = sum_i e_i * uhat[i][d] / sumE ; thread (dq, ig) does i = ig..1151 step 64
        float4 ps = make_float4(0.f, 0.f, 0.f, 0.f);
        for (int i = ig; i < 1152; i += 64) {
            const float4 uh = uhat4(ub + i * 8, wo + (size_t)i * 128 + d4);
            const float e = ebuf[i];
            ps.x += e * uh.x; ps.y += e * uh.y; ps.z += e * uh.z; ps.w += e * uh.w;
        }
        psum[ig][d4 + 0] = ps.x; psum[ig][d4 + 1] = ps.y;
        psum[ig][d4 + 2] = ps.z; psum[ig][d4 + 3] = ps.w;
        __syncthreads();
        if (t < 16) {
            float s = 0.f;
            for (int g = 0; g < 64; ++g) s += psum[g][t];
            s /= sumE;
            float q = s * s;
            q += __shfl_xor(q, 1, 16); q += __shfl_xor(q, 2, 16);
            q += __shfl_xor(q, 4, 16); q += __shfl_xor(q, 8, 16);
            v_s[t] = s * sqrtf(q) / (1.f + q);   // squash
        }
        __syncthreads();
        if (iter < 3) {
            const float v0 = v_s[d4 + 0], v1 = v_s[d4 + 1];
            const float v2 = v_s[d4 + 2], v3 = v_s[d4 + 3];
            for (int i = ig; i < 1152; i += 64) {
                const float4 uh = uhat4(ub + i * 8, wo + (size_t)i * 128 + d4);
                float pr = uh.x * v0 + uh.y * v1 + uh.z * v2 + uh.w * v3;
                pr += __shfl_xor(pr, 1, 64);
                pr += __shfl_xor(pr, 2, 64);
                if (dq == 0) logits[i] += pr;
            }
            __syncthreads();
        }
    }
    if (t < 16) out[((size_t)b * 10 + o) * 16 + t] = v_s[t];
}

extern "C" void kernel_launch(void* const* d_in, const int* in_sizes, int n_in,
                              void* d_out, int out_size, void* d_ws, size_t ws_size,
                              hipStream_t stream)
{
    const float* img = (const float*)d_in[0];
    const float* c1w = (const float*)d_in[1];
    const float* c1b = (const float*)d_in[2];
    const float* pw  = (const float*)d_in[3];
    const float* pb  = (const float*)d_in[4];
    const float* rw  = (const float*)d_in[5];
    float* out = (float*)d_out;
    char* ws = (char*)d_ws;
    float* x    = (float*)(ws);                            // 52,428,800 B
    float* part = (float*)(ws + 52428800);                 // 18,874,368 B
    float* u    = (float*)(ws + 52428800 + 18874368);      // 4,718,592 B

    hipLaunchKernelGGL(conv1_kernel, dim3(4, 128), dim3(256), 0, stream, img, c1w, c1b, x);
    hipLaunchKernelGGL(pcaps_kernel, dim3(128, 2, 4), dim3(192), 0, stream, x, pw, part);
    hipLaunchKernelGGL(squash_kernel, dim3(576), dim3(256), 0, stream, part, pb, u);
    hipLaunchKernelGGL(routing_kernel, dim3(128, 10), dim3(256), 0, stream, u, rw, out);
}

// Round 2
// 1055.337 us; speedup vs baseline: 1.2469x; 1.2469x over previous
//
#include <hip/hip_runtime.h>
#include <math.h>

// ---------------------------------------------------------------------------
// CapsuleNetwork forward, fp32.
//   K0 wtrans: route-free weight pre-transpose  w[256oc][256ic][81] ->
//              wT[2oct][256ic][81][128ocl]   (one contiguous slice per (oct,ic))
//   K1 conv1:  img[128,1,28,28] -> x[128,256,20,20]  (9x9, s1, relu+bias)
//   K2 pcaps:  x -> partial sums part[4][128][32][36][8]  (9x9, s2, 64-ic chunks)
//   K3 squash: part(+bias) -> u[128,1152,8]
//   K4 routing: u, route_w -> out[128,10,16]
// ---------------------------------------------------------------------------

__global__ __launch_bounds__(256) void wtrans_kernel(
    const float* __restrict__ w,   // [256][256][81]
    float* __restrict__ wT)        // [2][256][81][128]  (oct, ic, k, ocl)
{
    const int idx = blockIdx.x * 256 + threadIdx.x;   // float4 index
    if (idx >= 2 * 256 * 81 * 32) return;
    const int c   = idx & 31;                 // float4 within 128-oc row
    const int k   = (idx >> 5) % 81;
    const int ic  = ((idx >> 5) / 81) % 256;
    const int oct = idx / (32 * 81 * 256);
    const int ocb = oct * 128 + c * 4;
    float4 v;
    v.x = w[((size_t)(ocb + 0) * 256 + ic) * 81 + k];
    v.y = w[((size_t)(ocb + 1) * 256 + ic) * 81 + k];
    v.z = w[((size_t)(ocb + 2) * 256 + ic) * 81 + k];
    v.w = w[((size_t)(ocb + 3) * 256 + ic) * 81 + k];
    ((float4*)wT)[idx] = v;
}

__global__ __launch_bounds__(256) void conv1_kernel(
    const float* __restrict__ img,   // [128][28][28]
    const float* __restrict__ w,     // [256][9][9]
    const float* __restrict__ bias,  // [256]
    float* __restrict__ x)           // [128][256][20][20]
{
    const int ct = blockIdx.x;   // 0..3 (64-channel tile)
    const int b  = blockIdx.y;   // 0..127
    const int t  = threadIdx.x;
    __shared__ float img_s[784];
    __shared__ float w_s[64 * 81];
    for (int idx = t; idx < 784; idx += 256) img_s[idx] = img[b * 784 + idx];
    for (int idx = t; idx < 64 * 81; idx += 256) w_s[idx] = w[ct * 64 * 81 + idx];
    __syncthreads();
    for (int task = t; task < 1280; task += 256) {
        const int cl = task / 20;
        const int oy = task - cl * 20;
        float acc[20];
        const float bv = bias[ct * 64 + cl];
#pragma unroll
        for (int j = 0; j < 20; ++j) acc[j] = bv;
#pragma unroll
        for (int ky = 0; ky < 9; ++ky) {
            float rowv[28];
            const float* r = &img_s[(oy + ky) * 28];
#pragma unroll
            for (int j = 0; j < 28; ++j) rowv[j] = r[j];
#pragma unroll
            for (int kx = 0; kx < 9; ++kx) {
                const float wv = w_s[cl * 81 + ky * 9 + kx];
#pragma unroll
                for (int j = 0; j < 20; ++j) acc[j] += wv * rowv[j + kx];
            }
        }
        float* xp = x + (((size_t)b * 256 + ct * 64 + cl) * 400) + oy * 20;
#pragma unroll
        for (int j = 0; j < 20; ++j) xp[j] = fmaxf(acc[j], 0.f);
    }
}

// Block tile: 128 oc x 36 pos, 64-ic K-chunk. 192 threads: oc4=(t&31)*4,
// oy=t>>5 (one 6-wide output row per thread). Weights pre-transposed in wT so
// staging is a contiguous float4 copy (conflict-free) and compute reads
// w_s[k*128+oc4] (b128 conflict-free / broadcast).
__global__ __launch_bounds__(192) void pcaps_kernel(
    const float* __restrict__ x,    // [128][256][400]
    const float* __restrict__ wT,   // [2][256][81][128]
    float* __restrict__ part)       // [4][128][32][36][8]
{
    const int b   = blockIdx.x;  // 128
    const int oct = blockIdx.y;  // 2
    const int ict = blockIdx.z;  // 4
    const int t = threadIdx.x;
    __shared__ float w_s[81 * 128];
    __shared__ float x_s[400];
    const int oc4 = (t & 31) * 4;
    const int oy  = t >> 5;      // 0..5
    float acc[6][4];
#pragma unroll
    for (int p = 0; p < 6; ++p) {
        acc[p][0] = 0.f; acc[p][1] = 0.f; acc[p][2] = 0.f; acc[p][3] = 0.f;
    }
    const float* xb = x + (size_t)b * 102400 + (size_t)ict * 25600;
    const float4* wsrc = (const float4*)(wT + ((size_t)oct * 256 + ict * 64) * 81 * 128);
    for (int ic = 0; ic < 64; ++ic) {
        for (int idx = t; idx < 100; idx += 192)
            ((float4*)x_s)[idx] = ((const float4*)(xb + ic * 400))[idx];
        const float4* ws = wsrc + (size_t)ic * 2592;
        for (int idx = t; idx < 2592; idx += 192)
            ((float4*)w_s)[idx] = ws[idx];
        __syncthreads();
#pragma unroll
        for (int ky = 0; ky < 9; ++ky) {
            float rowv[20];
            const float4* xr = (const float4*)&x_s[(2 * oy + ky) * 20];
#pragma unroll
            for (int j = 0; j < 5; ++j) ((float4*)rowv)[j] = xr[j];
#pragma unroll
            for (int kx = 0; kx < 9; ++kx) {
                const float4 wv = *(const float4*)&w_s[(ky * 9 + kx) * 128 + oc4];
#pragma unroll
                for (int p = 0; p < 6; ++p) {
                    const float xv = rowv[2 * p + kx];
                    acc[p][0] += xv * wv.x; acc[p][1] += xv * wv.y;
                    acc[p][2] += xv * wv.z; acc[p][3] += xv * wv.w;
                }
            }
        }
        __syncthreads();
    }
    float* pb = part + ((size_t)ict * 128 + b) * 9216;
#pragma unroll
    for (int p = 0; p < 6; ++p) {
        const int pos = oy * 6 + p;
#pragma unroll
        for (int j = 0; j < 4; ++j) {
            const int oc  = oct * 128 + oc4 + j;
            const int cap = oc >> 3;
            const int d   = oc & 7;
            pb[((size_t)cap * 36 + pos) * 8 + d] = acc[p][j];
        }
    }
}

__global__ __launch_bounds__(256) void squash_kernel(
    const float* __restrict__ part,  // [4][128*1152][8]
    const float* __restrict__ bias,  // [256] = [32][8]
    float* __restrict__ u)           // [128*1152][8]
{
    const int idx = blockIdx.x * 256 + threadIdx.x;  // 0..147455
    if (idx >= 128 * 1152) return;
    const int i   = idx % 1152;
    const int cap = i / 36;
    float v[8];
    float n2 = 0.f;
#pragma unroll
    for (int c = 0; c < 8; ++c) {
        float s = bias[cap * 8 + c];
#pragma unroll
        for (int q = 0; q < 4; ++q) s += part[(size_t)q * 1179648 + (size_t)idx * 8 + c];
        v[c] = s;
        n2 += s * s;
    }
    const float sc = sqrtf(n2) / (1.f + n2);
#pragma unroll
    for (int c = 0; c < 8; ++c) u[(size_t)idx * 8 + c] = v[c] * sc;
}

__device__ __forceinline__ float4 uhat4(const float* __restrict__ urow,
                                        const float* __restrict__ wrow)
{
    float ur[8];
    const float4 u0 = *(const float4*)urow;
    const float4 u1 = *(const float4*)(urow + 4);
    ur[0] = u0.x; ur[1] = u0.y; ur[2] = u0.z; ur[3] = u0.w;
    ur[4] = u1.x; ur[5] = u1.y; ur[6] = u1.z; ur[7] = u1.w;
    float4 uh = make_float4(0.f, 0.f, 0.f, 0.f);
#pragma unroll
    for (int c = 0; c < 8; ++c) {
        const float4 wv = *(const float4*)(wrow + c * 16);
        uh.x += ur[c] * wv.x; uh.y += ur[c] * wv.y;
        uh.z += ur[c] * wv.z; uh.w += ur[c] * wv.w;
    }
    return uh;
}

__global__ __launch_bounds__(256) void routing_kernel(
    const float* __restrict__ u,    // [128][1152][8]
    const float* __restrict__ rw,   // [10][1152][8][16]
    float* __restrict__ out)        // [128][10][16]
{
    const int b = blockIdx.x;
    const int o = blockIdx.y;
    const int t = threadIdx.x;
    __shared__ float logits[1152];
    __shared__ float ebuf[1152];
    __shared__ float psum[64][17];
    __shared__ float red[8];
    __shared__ float v_s[16];
    const float* ub = u + (size_t)b * 9216;
    const float* wo = rw + (size_t)o * 147456;
    for (int i = t; i < 1152; i += 256) logits[i] = 0.f;
    __syncthreads();
    const int dq = t & 3;
    const int ig = t >> 2;
    const int d4 = dq * 4;
    for (int iter = 1; iter <= 3; ++iter) {
        float lmax = -3.0e38f;
        for (int i = t; i < 1152; i += 256) lmax = fmaxf(lmax, logits[i]);
#pragma unroll
        for (int off = 32; off; off >>= 1) lmax = fmaxf(lmax, __shfl_xor(lmax, off, 64));
        if ((t & 63) == 0) red[t >> 6] = lmax;
        __syncthreads();
        const float m = fmaxf(fmaxf(red[0], red[1]), fmaxf(red[2], red[3]));
        float ls = 0.f;
        for (int i = t; i < 1152; i += 256) {
            const float e = expf(logits[i] - m);
            ebuf[i] = e;
            ls += e;
        }
#pragma unroll
        for (int off = 32; off; off >>= 1) ls += __shfl_xor(ls, off, 64);
        if ((t & 63) == 0) red[4 + (t >> 6)] = ls;
        __syncthreads();
        const float sumE = red[4] + red[5] + red[6] + red[7];
        float4 ps = make_float4(0.f, 0.f, 0.f, 0.f);
        for (int i = ig; i < 1152; i += 64) {
            const float4 uh = uhat4(ub + i * 8, wo + (size_t)i * 128 + d4);
            const float e = ebuf[i];
            ps.x += e * uh.x; ps.y += e * uh.y; ps.z += e * uh.z; ps.w += e * uh.w;
        }
        psum[ig][d4 + 0] = ps.x; psum[ig][d4 + 1] = ps.y;
        psum[ig][d4 + 2] = ps.z; psum[ig][d4 + 3] = ps.w;
        __syncthreads();
        if (t < 16) {
            float s = 0.f;
            for (int g = 0; g < 64; ++g) s += psum[g][t];
            s /= sumE;
            float q = s * s;
            q += __shfl_xor(q, 1, 16); q += __shfl_xor(q, 2, 16);
            q += __shfl_xor(q, 4, 16); q += __shfl_xor(q, 8, 16);
            v_s[t] = s * sqrtf(q) / (1.f + q);
        }
        __syncthreads();
        if (iter < 3) {
            const float v0 = v_s[d4 + 0], v1 = v_s[d4 + 1];
            const float v2 = v_s[d4 + 2], v3 = v_s[d4 + 3];
            for (int i = ig; i < 1152; i += 64) {
                const float4 uh = uhat4(ub + i * 8, wo + (size_t)i * 128 + d4);
                float pr = uh.x * v0 + uh.y * v1 + uh.z * v2 + uh.w * v3;
                pr += __shfl_xor(pr, 1, 64);
                pr += __shfl_xor(pr, 2, 64);
                if (dq == 0) logits[i] += pr;
            }
            __syncthreads();
        }
    }
    if (t < 16) out[((size_t)b * 10 + o) * 16 + t] = v_s[t];
}

extern "C" void kernel_launch(void* const* d_in, const int* in_sizes, int n_in,
                              void* d_out, int out_size, void* d_ws, size_t ws_size,
                              hipStream_t stream)
{
    const float* img = (const float*)d_in[0];
    const float* c1w = (const float*)d_in[1];
    const float* c1b = (const float*)d_in[2];
    const float* pw  = (const float*)d_in[3];
    const float* pb  = (const float*)d_in[4];
    const float* rw  = (const float*)d_in[5];
    float* out = (float*)d_out;
    char* ws = (char*)d_ws;
    float* x    = (float*)(ws);                            // 52,428,800 B
    float* part = (float*)(ws + 52428800);                 // 18,874,368 B
    float* u    = (float*)(ws + 52428800 + 18874368);      //  4,718,592 B
    float* wT   = (float*)(ws + 52428800 + 18874368 + 4718592);  // 21,233,664 B

    hipLaunchKernelGGL(wtrans_kernel, dim3((2 * 256 * 81 * 32 + 255) / 256), dim3(256), 0, stream, pw, wT);
    hipLaunchKernelGGL(conv1_kernel, dim3(4, 128), dim3(256), 0, stream, img, c1w, c1b, x);
    hipLaunchKernelGGL(pcaps_kernel, dim3(128, 2, 4), dim3(192), 0, stream, x, wT, part);
    hipLaunchKernelGGL(squash_kernel, dim3(576), dim3(256), 0, stream, part, pb, u);
    hipLaunchKernelGGL(routing_kernel, dim3(128, 10), dim3(256), 0, stream, u, rw, out);
}

// Round 3
// 953.709 us; speedup vs baseline: 1.3798x; 1.1066x over previous
//
#include <hip/hip_runtime.h>
#include <math.h>

// ---------------------------------------------------------------------------
// CapsuleNetwork forward, fp32.
//   K0 wtrans: weight pre-transpose  w[256oc][256ic][81] ->
//              wT[2oct][256ic][81][128ocl]
//   K1 conv1:  img[128,1,28,28] -> x[128,256,20,20]  (9x9, s1, relu+bias)
//   K2 pcaps:  x -> part[4][128][32][36][8]  (9x9, s2, 64-ic chunks)
//              v3: 384 thr, 2 batches/block, register-prefetch double buffer
//   K3 squash: part(+bias) -> u[128,1152,8]
//   K4 routing: u, route_w -> out[128,10,16]
// ---------------------------------------------------------------------------

__global__ __launch_bounds__(256) void wtrans_kernel(
    const float* __restrict__ w,   // [256][256][81]
    float* __restrict__ wT)        // [2][256][81][128]  (oct, ic, k, ocl)
{
    const int idx = blockIdx.x * 256 + threadIdx.x;   // float4 index
    if (idx >= 2 * 256 * 81 * 32) return;
    const int c   = idx & 31;
    const int k   = (idx >> 5) % 81;
    const int ic  = ((idx >> 5) / 81) % 256;
    const int oct = idx / (32 * 81 * 256);
    const int ocb = oct * 128 + c * 4;
    float4 v;
    v.x = w[((size_t)(ocb + 0) * 256 + ic) * 81 + k];
    v.y = w[((size_t)(ocb + 1) * 256 + ic) * 81 + k];
    v.z = w[((size_t)(ocb + 2) * 256 + ic) * 81 + k];
    v.w = w[((size_t)(ocb + 3) * 256 + ic) * 81 + k];
    ((float4*)wT)[idx] = v;
}

__global__ __launch_bounds__(256) void conv1_kernel(
    const float* __restrict__ img,   // [128][28][28]
    const float* __restrict__ w,     // [256][9][9]
    const float* __restrict__ bias,  // [256]
    float* __restrict__ x)           // [128][256][20][20]
{
    const int ct = blockIdx.x;
    const int b  = blockIdx.y;
    const int t  = threadIdx.x;
    __shared__ float img_s[784];
    __shared__ float w_s[64 * 81];
    for (int idx = t; idx < 784; idx += 256) img_s[idx] = img[b * 784 + idx];
    for (int idx = t; idx < 64 * 81; idx += 256) w_s[idx] = w[ct * 64 * 81 + idx];
    __syncthreads();
    for (int task = t; task < 1280; task += 256) {
        const int cl = task / 20;
        const int oy = task - cl * 20;
        float acc[20];
        const float bv = bias[ct * 64 + cl];
#pragma unroll
        for (int j = 0; j < 20; ++j) acc[j] = bv;
#pragma unroll
        for (int ky = 0; ky < 9; ++ky) {
            float rowv[28];
            const float* r = &img_s[(oy + ky) * 28];
#pragma unroll
            for (int j = 0; j < 28; ++j) rowv[j] = r[j];
#pragma unroll
            for (int kx = 0; kx < 9; ++kx) {
                const float wv = w_s[cl * 81 + ky * 9 + kx];
#pragma unroll
                for (int j = 0; j < 20; ++j) acc[j] += wv * rowv[j + kx];
            }
        }
        float* xp = x + (((size_t)b * 256 + ct * 64 + cl) * 400) + oy * 20;
#pragma unroll
        for (int j = 0; j < 20; ++j) xp[j] = fmaxf(acc[j], 0.f);
    }
}

// 384 threads: oc4=(t&31)*4, slot=t>>5 in 0..11 -> (bb = slot/6, oy = slot%6).
// Two batches share one weight stage; next-ic stage is prefetched into
// registers before compute so global latency hides under the FMA phase.
__global__ __launch_bounds__(384) void pcaps_kernel(
    const float* __restrict__ x,    // [128][256][400]
    const float* __restrict__ wT,   // [2][256][81][128]
    float* __restrict__ part)       // [4][128][32][36][8]
{
    const int btile = blockIdx.x;  // 64
    const int oct   = blockIdx.y;  // 2
    const int ict   = blockIdx.z;  // 4
    const int t = threadIdx.x;
    __shared__ float w_s[81 * 128];   // 41472 B
    __shared__ float x_s[2][400];     //  3200 B
    const int oc4  = (t & 31) * 4;
    const int slot = t >> 5;          // 0..11
    const int bb   = (slot >= 6) ? 1 : 0;
    const int oy   = slot - 6 * bb;   // 0..5
    const int b0   = btile * 2;

    float acc[6][4];
#pragma unroll
    for (int p = 0; p < 6; ++p) {
        acc[p][0] = 0.f; acc[p][1] = 0.f; acc[p][2] = 0.f; acc[p][3] = 0.f;
    }

    const float* xb0 = x + (size_t)b0 * 102400 + (size_t)ict * 25600;
    const float* xb1 = xb0 + 102400;
    const float4* wsrc = (const float4*)(wT + ((size_t)oct * 256 + ict * 64) * 10368);

    float4 wreg[7];
    float4 xreg;

#define PCAPS_PREFETCH(ic_)                                                   \
    {                                                                         \
        const float4* wp = wsrc + (size_t)(ic_) * 2592;                       \
        _Pragma("unroll")                                                     \
        for (int j = 0; j < 7; ++j) {                                         \
            const int idx = t + j * 384;                                      \
            if (idx < 2592) wreg[j] = wp[idx];                                \
        }                                                                     \
        if (t < 100)      xreg = ((const float4*)(xb0 + (ic_) * 400))[t];     \
        else if (t < 200) xreg = ((const float4*)(xb1 + (ic_) * 400))[t-100]; \
    }

    PCAPS_PREFETCH(0);
    for (int ic = 0; ic < 64; ++ic) {
        __syncthreads();   // previous compute done reading LDS
        // commit prefetched stage to LDS
#pragma unroll
        for (int j = 0; j < 7; ++j) {
            const int idx = t + j * 384;
            if (idx < 2592) ((float4*)w_s)[idx] = wreg[j];
        }
        if (t < 100)      ((float4*)x_s[0])[t] = xreg;
        else if (t < 200) ((float4*)x_s[1])[t - 100] = xreg;
        __syncthreads();
        if (ic < 63) PCAPS_PREFETCH(ic + 1);
        // compute from LDS
        const float* xrow = x_s[bb];
#pragma unroll
        for (int ky = 0; ky < 9; ++ky) {
            float rowv[20];
            const float4* xr = (const float4*)&xrow[(2 * oy + ky) * 20];
#pragma unroll
            for (int j = 0; j < 5; ++j) ((float4*)rowv)[j] = xr[j];
#pragma unroll
            for (int kx = 0; kx < 9; ++kx) {
                const float4 wv = *(const float4*)&w_s[(ky * 9 + kx) * 128 + oc4];
#pragma unroll
                for (int p = 0; p < 6; ++p) {
                    const float xv = rowv[2 * p + kx];
                    acc[p][0] += xv * wv.x; acc[p][1] += xv * wv.y;
                    acc[p][2] += xv * wv.z; acc[p][3] += xv * wv.w;
                }
            }
        }
    }
#undef PCAPS_PREFETCH

    float* pb = part + ((size_t)ict * 128 + (b0 + bb)) * 9216;
#pragma unroll
    for (int p = 0; p < 6; ++p) {
        const int pos = oy * 6 + p;
#pragma unroll
        for (int j = 0; j < 4; ++j) {
            const int oc = oct * 128 + oc4 + j;
            pb[((size_t)(oc >> 3) * 36 + pos) * 8 + (oc & 7)] = acc[p][j];
        }
    }
}

__global__ __launch_bounds__(256) void squash_kernel(
    const float* __restrict__ part,  // [4][128*1152][8]
    const float* __restrict__ bias,  // [256] = [32][8]
    float* __restrict__ u)           // [128*1152][8]
{
    const int idx = blockIdx.x * 256 + threadIdx.x;
    if (idx >= 128 * 1152) return;
    const int i   = idx % 1152;
    const int cap = i / 36;
    float v[8];
    float n2 = 0.f;
#pragma unroll
    for (int c = 0; c < 8; ++c) {
        float s = bias[cap * 8 + c];
#pragma unroll
        for (int q = 0; q < 4; ++q) s += part[(size_t)q * 1179648 + (size_t)idx * 8 + c];
        v[c] = s;
        n2 += s * s;
    }
    const float sc = sqrtf(n2) / (1.f + n2);
#pragma unroll
    for (int c = 0; c < 8; ++c) u[(size_t)idx * 8 + c] = v[c] * sc;
}

__device__ __forceinline__ float4 uhat4(const float* __restrict__ urow,
                                        const float* __restrict__ wrow)
{
    float ur[8];
    const float4 u0 = *(const float4*)urow;
    const float4 u1 = *(const float4*)(urow + 4);
    ur[0] = u0.x; ur[1] = u0.y; ur[2] = u0.z; ur[3] = u0.w;
    ur[4] = u1.x; ur[5] = u1.y; ur[6] = u1.z; ur[7] = u1.w;
    float4 uh = make_float4(0.f, 0.f, 0.f, 0.f);
#pragma unroll
    for (int c = 0; c < 8; ++c) {
        const float4 wv = *(const float4*)(wrow + c * 16);
        uh.x += ur[c] * wv.x; uh.y += ur[c] * wv.y;
        uh.z += ur[c] * wv.z; uh.w += ur[c] * wv.w;
    }
    return uh;
}

__global__ __launch_bounds__(256) void routing_kernel(
    const float* __restrict__ u,    // [128][1152][8]
    const float* __restrict__ rw,   // [10][1152][8][16]
    float* __restrict__ out)        // [128][10][16]
{
    const int b = blockIdx.x;
    const int o = blockIdx.y;
    const int t = threadIdx.x;
    __shared__ float logits[1152];
    __shared__ float ebuf[1152];
    __shared__ float psum[64][17];
    __shared__ float red[8];
    __shared__ float v_s[16];
    const float* ub = u + (size_t)b * 9216;
    const float* wo = rw + (size_t)o * 147456;
    for (int i = t; i < 1152; i += 256) logits[i] = 0.f;
    __syncthreads();
    const int dq = t & 3;
    const int ig = t >> 2;
    const int d4 = dq * 4;
    for (int iter = 1; iter <= 3; ++iter) {
        float lmax = -3.0e38f;
        for (int i = t; i < 1152; i += 256) lmax = fmaxf(lmax, logits[i]);
#pragma unroll
        for (int off = 32; off; off >>= 1) lmax = fmaxf(lmax, __shfl_xor(lmax, off, 64));
        if ((t & 63) == 0) red[t >> 6] = lmax;
        __syncthreads();
        const float m = fmaxf(fmaxf(red[0], red[1]), fmaxf(red[2], red[3]));
        float ls = 0.f;
        for (int i = t; i < 1152; i += 256) {
            const float e = expf(logits[i] - m);
            ebuf[i] = e;
            ls += e;
        }
#pragma unroll
        for (int off = 32; off; off >>= 1) ls += __shfl_xor(ls, off, 64);
        if ((t & 63) == 0) red[4 + (t >> 6)] = ls;
        __syncthreads();
        const float sumE = red[4] + red[5] + red[6] + red[7];
        float4 ps = make_float4(0.f, 0.f, 0.f, 0.f);
        for (int i = ig; i < 1152; i += 64) {
            const float4 uh = uhat4(ub + i * 8, wo + (size_t)i * 128 + d4);
            const float e = ebuf[i];
            ps.x += e * uh.x; ps.y += e * uh.y; ps.z += e * uh.z; ps.w += e * uh.w;
        }
        psum[ig][d4 + 0] = ps.x; psum[ig][d4 + 1] = ps.y;
        psum[ig][d4 + 2] = ps.z; psum[ig][d4 + 3] = ps.w;
        __syncthreads();
        if (t < 16) {
            float s = 0.f;
            for (int g = 0; g < 64; ++g) s += psum[g][t];
            s /= sumE;
            float q = s * s;
            q += __shfl_xor(q, 1, 16); q += __shfl_xor(q, 2, 16);
            q += __shfl_xor(q, 4, 16); q += __shfl_xor(q, 8, 16);
            v_s[t] = s * sqrtf(q) / (1.f + q);
        }
        __syncthreads();
        if (iter < 3) {
            const float v0 = v_s[d4 + 0], v1 = v_s[d4 + 1];
            const float v2 = v_s[d4 + 2], v3 = v_s[d4 + 3];
            for (int i = ig; i < 1152; i += 64) {
                const float4 uh = uhat4(ub + i * 8, wo + (size_t)i * 128 + d4);
                float pr = uh.x * v0 + uh.y * v1 + uh.z * v2 + uh.w * v3;
                pr += __shfl_xor(pr, 1, 64);
                pr += __shfl_xor(pr, 2, 64);
                if (dq == 0) logits[i] += pr;
            }
            __syncthreads();
        }
    }
    if (t < 16) out[((size_t)b * 10 + o) * 16 + t] = v_s[t];
}

extern "C" void kernel_launch(void* const* d_in, const int* in_sizes, int n_in,
                              void* d_out, int out_size, void* d_ws, size_t ws_size,
                              hipStream_t stream)
{
    const float* img = (const float*)d_in[0];
    const float* c1w = (const float*)d_in[1];
    const float* c1b = (const float*)d_in[2];
    const float* pw  = (const float*)d_in[3];
    const float* pb  = (const float*)d_in[4];
    const float* rw  = (const float*)d_in[5];
    float* out = (float*)d_out;
    char* ws = (char*)d_ws;
    float* x    = (float*)(ws);                            // 52,428,800 B
    float* part = (float*)(ws + 52428800);                 // 18,874,368 B
    float* u    = (float*)(ws + 52428800 + 18874368);      //  4,718,592 B
    float* wT   = (float*)(ws + 52428800 + 18874368 + 4718592);  // 21,233,664 B

    hipLaunchKernelGGL(wtrans_kernel, dim3((2 * 256 * 81 * 32 + 255) / 256), dim3(256), 0, stream, pw, wT);
    hipLaunchKernelGGL(conv1_kernel, dim3(4, 128), dim3(256), 0, stream, img, c1w, c1b, x);
    hipLaunchKernelGGL(pcaps_kernel, dim3(64, 2, 4), dim3(384), 0, stream, x, wT, part);
    hipLaunchKernelGGL(squash_kernel, dim3(576), dim3(256), 0, stream, part, pb, u);
    hipLaunchKernelGGL(routing_kernel, dim3(128, 10), dim3(256), 0, stream, u, rw, out);
}

// Round 4
// 940.316 us; speedup vs baseline: 1.3995x; 1.0142x over previous
//
#include <hip/hip_runtime.h>
#include <math.h>

// ---------------------------------------------------------------------------
// CapsuleNetwork forward, fp32.
//   K0 wtrans: weight pre-transpose  w[256oc][256ic][81] ->
//              wT[2oct][256ic][2688 float4]  (81*128 real + 96 float4 pad so
//              pcaps staging is exactly 7 float4/thread, branch-free)
//   K1 conv1:  img[128,1,28,28] -> x[128,256,20,20]  (9x9, s1, relu+bias)
//   K2 pcaps:  x -> part[4][128][32][36][8]  (9x9, s2, 64-ic chunks)
//              384 thr, 2 batches/block, branch-free register double buffer
//   K3 squash: part(+bias) -> u[128,1152,8]
//   K4 routing: u, route_w -> out[128,10,16]
// ---------------------------------------------------------------------------

#define WSLICE 2688   // float4 per (oct, ic) weight slice (2592 real + 96 pad)

__global__ __launch_bounds__(256) void wtrans_kernel(
    const float* __restrict__ w,   // [256][256][81]
    float* __restrict__ wT)        // [2][256][WSLICE float4]
{
    const int idx = blockIdx.x * 256 + threadIdx.x;   // real float4 index
    if (idx >= 2 * 256 * 81 * 32) return;
    const int c   = idx & 31;
    const int k   = (idx >> 5) % 81;
    const int ic  = ((idx >> 5) / 81) % 256;
    const int oct = idx / (32 * 81 * 256);
    const int ocb = oct * 128 + c * 4;
    float4 v;
    v.x = w[((size_t)(ocb + 0) * 256 + ic) * 81 + k];
    v.y = w[((size_t)(ocb + 1) * 256 + ic) * 81 + k];
    v.z = w[((size_t)(ocb + 2) * 256 + ic) * 81 + k];
    v.w = w[((size_t)(ocb + 3) * 256 + ic) * 81 + k];
    ((float4*)wT)[((size_t)oct * 256 + ic) * WSLICE + k * 32 + c] = v;
}

__global__ __launch_bounds__(256) void conv1_kernel(
    const float* __restrict__ img,   // [128][28][28]
    const float* __restrict__ w,     // [256][9][9]
    const float* __restrict__ bias,  // [256]
    float* __restrict__ x)           // [128][256][20][20]
{
    const int ct = blockIdx.x;
    const int b  = blockIdx.y;
    const int t  = threadIdx.x;
    __shared__ float img_s[784];
    __shared__ float w_s[64 * 81];
    for (int idx = t; idx < 784; idx += 256) img_s[idx] = img[b * 784 + idx];
    for (int idx = t; idx < 64 * 81; idx += 256) w_s[idx] = w[ct * 64 * 81 + idx];
    __syncthreads();
    for (int task = t; task < 1280; task += 256) {
        const int cl = task / 20;
        const int oy = task - cl * 20;
        float acc[20];
        const float bv = bias[ct * 64 + cl];
#pragma unroll
        for (int j = 0; j < 20; ++j) acc[j] = bv;
#pragma unroll
        for (int ky = 0; ky < 9; ++ky) {
            float rowv[28];
            const float* r = &img_s[(oy + ky) * 28];
#pragma unroll
            for (int j = 0; j < 28; ++j) rowv[j] = r[j];
#pragma unroll
            for (int kx = 0; kx < 9; ++kx) {
                const float wv = w_s[cl * 81 + ky * 9 + kx];
#pragma unroll
                for (int j = 0; j < 20; ++j) acc[j] += wv * rowv[j + kx];
            }
        }
        float* xp = x + (((size_t)b * 256 + ct * 64 + cl) * 400) + oy * 20;
#pragma unroll
        for (int j = 0; j < 20; ++j) xp[j] = fmaxf(acc[j], 0.f);
    }
}

// 384 threads: oc4=(t&31)*4, slot=t>>5 in 0..11 -> (bb = slot/6, oy = slot%6).
// Two batches share one weight stage; next-ic stage is prefetched into exactly
// 7 float4 regs/thread (branch-free, padded slice) so nothing spills.
__global__ __launch_bounds__(384, 3) void pcaps_kernel(
    const float* __restrict__ x,    // [128][256][400]
    const float* __restrict__ wT,   // [2][256][WSLICE float4]
    float* __restrict__ part)       // [4][128][32][36][8]
{
    const int btile = blockIdx.x;  // 64
    const int oct   = blockIdx.y;  // 2
    const int ict   = blockIdx.z;  // 4
    const int t = threadIdx.x;
    __shared__ float w_s[WSLICE * 4];   // 43008 B (81*128 real + pad)
    __shared__ float x_s[2][400];       //  3200 B
    const int oc4  = (t & 31) * 4;
    const int slot = t >> 5;          // 0..11
    const int bb   = (slot >= 6) ? 1 : 0;
    const int oy   = slot - 6 * bb;   // 0..5
    const int b0   = btile * 2;

    float acc[6][4];
#pragma unroll
    for (int p = 0; p < 6; ++p) {
        acc[p][0] = 0.f; acc[p][1] = 0.f; acc[p][2] = 0.f; acc[p][3] = 0.f;
    }

    const float* xb0 = x + (size_t)b0 * 102400 + (size_t)ict * 25600;
    const float* xb1 = xb0 + 102400;
    const float4* wsrc = (const float4*)wT + ((size_t)oct * 256 + ict * 64) * WSLICE;

    float4 wreg[7];
    float4 xreg;

#define PCAPS_PREFETCH(ic_)                                                   \
    {                                                                         \
        const float4* wp = wsrc + (size_t)(ic_) * WSLICE + t;                 \
        _Pragma("unroll")                                                     \
        for (int j = 0; j < 7; ++j) wreg[j] = wp[j * 384];                    \
        if (t < 100)      xreg = ((const float4*)(xb0 + (ic_) * 400))[t];     \
        else if (t < 200) xreg = ((const float4*)(xb1 + (ic_) * 400))[t-100]; \
    }

    PCAPS_PREFETCH(0);
    for (int ic = 0; ic < 64; ++ic) {
        __syncthreads();   // previous compute done reading LDS
#pragma unroll
        for (int j = 0; j < 7; ++j)
            ((float4*)w_s)[t + j * 384] = wreg[j];
        if (t < 100)      ((float4*)x_s[0])[t] = xreg;
        else if (t < 200) ((float4*)x_s[1])[t - 100] = xreg;
        __syncthreads();
        if (ic < 63) PCAPS_PREFETCH(ic + 1);
        const float* xrow = x_s[bb];
#pragma unroll
        for (int ky = 0; ky < 9; ++ky) {
            float rowv[20];
            const float4* xr = (const float4*)&xrow[(2 * oy + ky) * 20];
#pragma unroll
            for (int j = 0; j < 5; ++j) ((float4*)rowv)[j] = xr[j];
#pragma unroll
            for (int kx = 0; kx < 9; ++kx) {
                const float4 wv = *(const float4*)&w_s[(ky * 9 + kx) * 128 + oc4];
#pragma unroll
                for (int p = 0; p < 6; ++p) {
                    const float xv = rowv[2 * p + kx];
                    acc[p][0] += xv * wv.x; acc[p][1] += xv * wv.y;
                    acc[p][2] += xv * wv.z; acc[p][3] += xv * wv.w;
                }
            }
        }
    }
#undef PCAPS_PREFETCH

    float* pb = part + ((size_t)ict * 128 + (b0 + bb)) * 9216;
#pragma unroll
    for (int p = 0; p < 6; ++p) {
        const int pos = oy * 6 + p;
#pragma unroll
        for (int j = 0; j < 4; ++j) {
            const int oc = oct * 128 + oc4 + j;
            pb[((size_t)(oc >> 3) * 36 + pos) * 8 + (oc & 7)] = acc[p][j];
        }
    }
}

__global__ __launch_bounds__(256) void squash_kernel(
    const float* __restrict__ part,  // [4][128*1152][8]
    const float* __restrict__ bias,  // [256] = [32][8]
    float* __restrict__ u)           // [128*1152][8]
{
    const int idx = blockIdx.x * 256 + threadIdx.x;
    if (idx >= 128 * 1152) return;
    const int i   = idx % 1152;
    const int cap = i / 36;
    float v[8];
    float n2 = 0.f;
#pragma unroll
    for (int c = 0; c < 8; ++c) {
        float s = bias[cap * 8 + c];
#pragma unroll
        for (int q = 0; q < 4; ++q) s += part[(size_t)q * 1179648 + (size_t)idx * 8 + c];
        v[c] = s;
        n2 += s * s;
    }
    const float sc = sqrtf(n2) / (1.f + n2);
#pragma unroll
    for (int c = 0; c < 8; ++c) u[(size_t)idx * 8 + c] = v[c] * sc;
}

__device__ __forceinline__ float4 uhat4(const float* __restrict__ urow,
                                        const float* __restrict__ wrow)
{
    float ur[8];
    const float4 u0 = *(const float4*)urow;
    const float4 u1 = *(const float4*)(urow + 4);
    ur[0] = u0.x; ur[1] = u0.y; ur[2] = u0.z; ur[3] = u0.w;
    ur[4] = u1.x; ur[5] = u1.y; ur[6] = u1.z; ur[7] = u1.w;
    float4 uh = make_float4(0.f, 0.f, 0.f, 0.f);
#pragma unroll
    for (int c = 0; c < 8; ++c) {
        const float4 wv = *(const float4*)(wrow + c * 16);
        uh.x += ur[c] * wv.x; uh.y += ur[c] * wv.y;
        uh.z += ur[c] * wv.z; uh.w += ur[c] * wv.w;
    }
    return uh;
}

__global__ __launch_bounds__(256) void routing_kernel(
    const float* __restrict__ u,    // [128][1152][8]
    const float* __restrict__ rw,   // [10][1152][8][16]
    float* __restrict__ out)        // [128][10][16]
{
    const int b = blockIdx.x;
    const int o = blockIdx.y;
    const int t = threadIdx.x;
    __shared__ float logits[1152];
    __shared__ float ebuf[1152];
    __shared__ float psum[64][17];
    __shared__ float red[8];
    __shared__ float v_s[16];
    const float* ub = u + (size_t)b * 9216;
    const float* wo = rw + (size_t)o * 147456;
    for (int i = t; i < 1152; i += 256) logits[i] = 0.f;
    __syncthreads();
    const int dq = t & 3;
    const int ig = t >> 2;
    const int d4 = dq * 4;
    for (int iter = 1; iter <= 3; ++iter) {
        float lmax = -3.0e38f;
        for (int i = t; i < 1152; i += 256) lmax = fmaxf(lmax, logits[i]);
#pragma unroll
        for (int off = 32; off; off >>= 1) lmax = fmaxf(lmax, __shfl_xor(lmax, off, 64));
        if ((t & 63) == 0) red[t >> 6] = lmax;
        __syncthreads();
        const float m = fmaxf(fmaxf(red[0], red[1]), fmaxf(red[2], red[3]));
        float ls = 0.f;
        for (int i = t; i < 1152; i += 256) {
            const float e = expf(logits[i] - m);
            ebuf[i] = e;
            ls += e;
        }
#pragma unroll
        for (int off = 32; off; off >>= 1) ls += __shfl_xor(ls, off, 64);
        if ((t & 63) == 0) red[4 + (t >> 6)] = ls;
        __syncthreads();
        const float sumE = red[4] + red[5] + red[6] + red[7];
        float4 ps = make_float4(0.f, 0.f, 0.f, 0.f);
        for (int i = ig; i < 1152; i += 64) {
            const float4 uh = uhat4(ub + i * 8, wo + (size_t)i * 128 + d4);
            const float e = ebuf[i];
            ps.x += e * uh.x; ps.y += e * uh.y; ps.z += e * uh.z; ps.w += e * uh.w;
        }
        psum[ig][d4 + 0] = ps.x; psum[ig][d4 + 1] = ps.y;
        psum[ig][d4 + 2] = ps.z; psum[ig][d4 + 3] = ps.w;
        __syncthreads();
        if (t < 16) {
            float s = 0.f;
            for (int g = 0; g < 64; ++g) s += psum[g][t];
            s /= sumE;
            float q = s * s;
            q += __shfl_xor(q, 1, 16); q += __shfl_xor(q, 2, 16);
            q += __shfl_xor(q, 4, 16); q += __shfl_xor(q, 8, 16);
            v_s[t] = s * sqrtf(q) / (1.f + q);
        }
        __syncthreads();
        if (iter < 3) {
            const float v0 = v_s[d4 + 0], v1 = v_s[d4 + 1];
            const float v2 = v_s[d4 + 2], v3 = v_s[d4 + 3];
            for (int i = ig; i < 1152; i += 64) {
                const float4 uh = uhat4(ub + i * 8, wo + (size_t)i * 128 + d4);
                float pr = uh.x * v0 + uh.y * v1 + uh.z * v2 + uh.w * v3;
                pr += __shfl_xor(pr, 1, 64);
                pr += __shfl_xor(pr, 2, 64);
                if (dq == 0) logits[i] += pr;
            }
            __syncthreads();
        }
    }
    if (t < 16) out[((size_t)b * 10 + o) * 16 + t] = v_s[t];
}

extern "C" void kernel_launch(void* const* d_in, const int* in_sizes, int n_in,
                              void* d_out, int out_size, void* d_ws, size_t ws_size,
                              hipStream_t stream)
{
    const float* img = (const float*)d_in[0];
    const float* c1w = (const float*)d_in[1];
    const float* c1b = (const float*)d_in[2];
    const float* pw  = (const float*)d_in[3];
    const float* pb  = (const float*)d_in[4];
    const float* rw  = (const float*)d_in[5];
    float* out = (float*)d_out;
    char* ws = (char*)d_ws;
    float* x    = (float*)(ws);                            // 52,428,800 B
    float* part = (float*)(ws + 52428800);                 // 18,874,368 B
    float* u    = (float*)(ws + 52428800 + 18874368);      //  4,718,592 B
    float* wT   = (float*)(ws + 52428800 + 18874368 + 4718592);  // 22,020,096 B

    hipLaunchKernelGGL(wtrans_kernel, dim3((2 * 256 * 81 * 32 + 255) / 256), dim3(256), 0, stream, pw, wT);
    hipLaunchKernelGGL(conv1_kernel, dim3(4, 128), dim3(256), 0, stream, img, c1w, c1b, x);
    hipLaunchKernelGGL(pcaps_kernel, dim3(64, 2, 4), dim3(384), 0, stream, x, wT, part);
    hipLaunchKernelGGL(squash_kernel, dim3(576), dim3(256), 0, stream, part, pb, u);
    hipLaunchKernelGGL(routing_kernel, dim3(128, 10), dim3(256), 0, stream, u, rw, out);
}

// Round 5
// 816.795 us; speedup vs baseline: 1.6111x; 1.1512x over previous
//
#include <hip/hip_runtime.h>
#include <math.h>

// ---------------------------------------------------------------------------
// CapsuleNetwork forward, fp32.
//   K0 wtrans: w[256oc][256ic][81] -> wT[4 octile][256 ic][1344 float4]
//              (k-major, 64-oc rows of 16 float4; 1296 real + 48 pad so each
//              (octile,ic) slice is exactly 21 x 1KB wave-chunks)
//   K1 conv1:  img[128,1,28,28] -> x[128,256,20,20]
//   K2 pcaps:  2-phase pipelined implicit conv via global_load_lds:
//              64-oc x 36-pos x 4-batch block, 64-ic K loop, LDS double-buffer.
//   K3 squash: part(+bias) -> u[128,1152,8]
//   K4 routing: u, route_w -> out[128,10,16]
// ---------------------------------------------------------------------------

#define WSL4 1344          // float4 per (octile, ic) weight slice (1296 real + 48 pad)
#define XSL4 448           // float4 per x stage (400 real + 48 pad)

__device__ __forceinline__ void gl_lds16(const void* g, const void* lds_uniform_base) {
    __builtin_amdgcn_global_load_lds(
        (const __attribute__((address_space(1))) void*)g,
        (__attribute__((address_space(3))) void*)lds_uniform_base,
        16, 0, 0);
}

__global__ __launch_bounds__(256) void wtrans_kernel(
    const float* __restrict__ w,   // [256][256][81]
    float* __restrict__ wT)        // [4][256][WSL4 float4]
{
    const int idx = blockIdx.x * 256 + threadIdx.x;   // real float4 index
    if (idx >= 4 * 256 * 81 * 16) return;
    const int c      = idx & 15;
    const int k      = (idx >> 4) % 81;
    const int ic     = ((idx >> 4) / 81) % 256;
    const int octile = idx / (16 * 81 * 256);
    const int ocb    = octile * 64 + c * 4;
    float4 v;
    v.x = w[((size_t)(ocb + 0) * 256 + ic) * 81 + k];
    v.y = w[((size_t)(ocb + 1) * 256 + ic) * 81 + k];
    v.z = w[((size_t)(ocb + 2) * 256 + ic) * 81 + k];
    v.w = w[((size_t)(ocb + 3) * 256 + ic) * 81 + k];
    ((float4*)wT)[((size_t)octile * 256 + ic) * WSL4 + k * 16 + c] = v;
}

__global__ __launch_bounds__(256) void conv1_kernel(
    const float* __restrict__ img,   // [128][28][28]
    const float* __restrict__ w,     // [256][9][9]
    const float* __restrict__ bias,  // [256]
    float* __restrict__ x)           // [128][256][20][20]
{
    const int ct = blockIdx.x;
    const int b  = blockIdx.y;
    const int t  = threadIdx.x;
    __shared__ float img_s[784];
    __shared__ float w_s[64 * 81];
    for (int idx = t; idx < 784; idx += 256) img_s[idx] = img[b * 784 + idx];
    for (int idx = t; idx < 64 * 81; idx += 256) w_s[idx] = w[ct * 64 * 81 + idx];
    __syncthreads();
    for (int task = t; task < 1280; task += 256) {
        const int cl = task / 20;
        const int oy = task - cl * 20;
        float acc[20];
        const float bv = bias[ct * 64 + cl];
#pragma unroll
        for (int j = 0; j < 20; ++j) acc[j] = bv;
#pragma unroll
        for (int ky = 0; ky < 9; ++ky) {
            float rowv[28];
            const float* r = &img_s[(oy + ky) * 28];
#pragma unroll
            for (int j = 0; j < 28; ++j) rowv[j] = r[j];
#pragma unroll
            for (int kx = 0; kx < 9; ++kx) {
                const float wv = w_s[cl * 81 + ky * 9 + kx];
#pragma unroll
                for (int j = 0; j < 20; ++j) acc[j] += wv * rowv[j + kx];
            }
        }
        float* xp = x + (((size_t)b * 256 + ct * 64 + cl) * 400) + oy * 20;
#pragma unroll
        for (int j = 0; j < 20; ++j) xp[j] = fmaxf(acc[j], 0.f);
    }
}

// 384 threads = 6 waves. ocg = t&15 (4 oc each, 64 oc total); slot = t>>4 in
// 0..23: bb = slot/6 (4 batches), oy = slot%6. Staging is pure async
// global_load_lds into the off buffer; one __syncthreads per ic (its implicit
// vmcnt(0) drain is the wait-late point of the 2-phase pipeline).
__global__ __launch_bounds__(384) void pcaps_kernel(
    const float* __restrict__ x,    // [128][256][400]
    const float* __restrict__ wT,   // [4][256][WSL4 float4]
    float* __restrict__ part)       // [4][128][32][36][8]
{
    const int btile  = blockIdx.x;  // 32
    const int octile = blockIdx.y;  // 4
    const int ict    = blockIdx.z;  // 4
    const int t    = threadIdx.x;
    const int wave = t >> 6;        // 0..5
    const int lane = t & 63;
    __shared__ float4 w_s[2][WSL4];   // 43,008 B
    __shared__ float4 x_s[2][XSL4];   // 14,336 B
    const int oc4  = (t & 15) * 4;
    const int slot = t >> 4;          // 0..23
    const int bb   = slot / 6;        // 0..3
    const int oy   = slot - 6 * bb;   // 0..5
    const int b0   = btile * 4;

    float acc[6][4];
#pragma unroll
    for (int p = 0; p < 6; ++p) {
        acc[p][0] = 0.f; acc[p][1] = 0.f; acc[p][2] = 0.f; acc[p][3] = 0.f;
    }

    const float*  xg   = x + (size_t)b0 * 102400 + (size_t)ict * 25600;
    const float4* wsrc = (const float4*)wT + ((size_t)octile * 256 + ict * 64) * WSL4;

    // stage ic-slice into buffer bf (async; completes at next __syncthreads)
#define PCAPS_STAGE(bf_, ic_)                                                  \
    {                                                                          \
        const float4* gsl = wsrc + (size_t)(ic_) * WSL4;                       \
        for (int ch = wave; ch < 21; ch += 6)                                  \
            gl_lds16(gsl + ch * 64 + lane, &w_s[bf_][ch * 64]);                \
        for (int ch = wave; ch < 7; ch += 6) {                                 \
            int idx = ch * 64 + lane;                                          \
            if (idx >= 400) idx = 0;                                           \
            const int xbb = idx / 100;                                         \
            const int off = idx - xbb * 100;                                   \
            const float* g = xg + (size_t)xbb * 102400 + (ic_) * 400 + off * 4;\
            gl_lds16(g, &x_s[bf_][ch * 64]);                                   \
        }                                                                      \
    }

    PCAPS_STAGE(0, 0);
    __syncthreads();
    int buf = 0;
    for (int ic = 0; ic < 64; ++ic) {
        if (ic < 63) PCAPS_STAGE(buf ^ 1, ic + 1);
        const float* xrow = (const float*)x_s[buf] + bb * 400;
        const float* wrow = (const float*)w_s[buf];
#pragma unroll
        for (int ky = 0; ky < 9; ++ky) {
            float rowv[20];
            const float4* xr = (const float4*)&xrow[(2 * oy + ky) * 20];
#pragma unroll
            for (int j = 0; j < 5; ++j) ((float4*)rowv)[j] = xr[j];
#pragma unroll
            for (int kx = 0; kx < 9; ++kx) {
                const float4 wv = *(const float4*)&wrow[(ky * 9 + kx) * 64 + oc4];
#pragma unroll
                for (int p = 0; p < 6; ++p) {
                    const float xv = rowv[2 * p + kx];
                    acc[p][0] += xv * wv.x; acc[p][1] += xv * wv.y;
                    acc[p][2] += xv * wv.z; acc[p][3] += xv * wv.w;
                }
            }
        }
        __syncthreads();   // drains vmcnt(0): prefetch into buf^1 now visible
        buf ^= 1;
    }
#undef PCAPS_STAGE

    float* pb = part + ((size_t)ict * 128 + (b0 + bb)) * 9216;
    const int oc0 = octile * 64 + oc4;       // d0 = oc0 & 7 is 0 or 4
    const int cap = oc0 >> 3;
    const int d0  = oc0 & 7;
#pragma unroll
    for (int p = 0; p < 6; ++p) {
        const int pos = oy * 6 + p;
        *(float4*)&pb[((size_t)cap * 36 + pos) * 8 + d0] =
            make_float4(acc[p][0], acc[p][1], acc[p][2], acc[p][3]);
    }
}

__global__ __launch_bounds__(256) void squash_kernel(
    const float* __restrict__ part,  // [4][128*1152][8]
    const float* __restrict__ bias,  // [256] = [32][8]
    float* __restrict__ u)           // [128*1152][8]
{
    const int idx = blockIdx.x * 256 + threadIdx.x;
    if (idx >= 128 * 1152) return;
    const int i   = idx % 1152;
    const int cap = i / 36;
    float v[8];
    float n2 = 0.f;
#pragma unroll
    for (int c = 0; c < 8; ++c) {
        float s = bias[cap * 8 + c];
#pragma unroll
        for (int q = 0; q < 4; ++q) s += part[(size_t)q * 1179648 + (size_t)idx * 8 + c];
        v[c] = s;
        n2 += s * s;
    }
    const float sc = sqrtf(n2) / (1.f + n2);
#pragma unroll
    for (int c = 0; c < 8; ++c) u[(size_t)idx * 8 + c] = v[c] * sc;
}

__device__ __forceinline__ float4 uhat4(const float* __restrict__ urow,
                                        const float* __restrict__ wrow)
{
    float ur[8];
    const float4 u0 = *(const float4*)urow;
    const float4 u1 = *(const float4*)(urow + 4);
    ur[0] = u0.x; ur[1] = u0.y; ur[2] = u0.z; ur[3] = u0.w;
    ur[4] = u1.x; ur[5] = u1.y; ur[6] = u1.z; ur[7] = u1.w;
    float4 uh = make_float4(0.f, 0.f, 0.f, 0.f);
#pragma unroll
    for (int c = 0; c < 8; ++c) {
        const float4 wv = *(const float4*)(wrow + c * 16);
        uh.x += ur[c] * wv.x; uh.y += ur[c] * wv.y;
        uh.z += ur[c] * wv.z; uh.w += ur[c] * wv.w;
    }
    return uh;
}

__global__ __launch_bounds__(256) void routing_kernel(
    const float* __restrict__ u,    // [128][1152][8]
    const float* __restrict__ rw,   // [10][1152][8][16]
    float* __restrict__ out)        // [128][10][16]
{
    const int b = blockIdx.x;
    const int o = blockIdx.y;
    const int t = threadIdx.x;
    __shared__ float logits[1152];
    __shared__ float ebuf[1152];
    __shared__ float psum[64][17];
    __shared__ float red[8];
    __shared__ float v_s[16];
    const float* ub = u + (size_t)b * 9216;
    const float* wo = rw + (size_t)o * 147456;
    for (int i = t; i < 1152; i += 256) logits[i] = 0.f;
    __syncthreads();
    const int dq = t & 3;
    const int ig = t >> 2;
    const int d4 = dq * 4;
    for (int iter = 1; iter <= 3; ++iter) {
        float lmax = -3.0e38f;
        for (int i = t; i < 1152; i += 256) lmax = fmaxf(lmax, logits[i]);
#pragma unroll
        for (int off = 32; off; off >>= 1) lmax = fmaxf(lmax, __shfl_xor(lmax, off, 64));
        if ((t & 63) == 0) red[t >> 6] = lmax;
        __syncthreads();
        const float m = fmaxf(fmaxf(red[0], red[1]), fmaxf(red[2], red[3]));
        float ls = 0.f;
        for (int i = t; i < 1152; i += 256) {
            const float e = expf(logits[i] - m);
            ebuf[i] = e;
            ls += e;
        }
#pragma unroll
        for (int off = 32; off; off >>= 1) ls += __shfl_xor(ls, off, 64);
        if ((t & 63) == 0) red[4 + (t >> 6)] = ls;
        __syncthreads();
        const float sumE = red[4] + red[5] + red[6] + red[7];
        float4 ps = make_float4(0.f, 0.f, 0.f, 0.f);
        for (int i = ig; i < 1152; i += 64) {
            const float4 uh = uhat4(ub + i * 8, wo + (size_t)i * 128 + d4);
            const float e = ebuf[i];
            ps.x += e * uh.x; ps.y += e * uh.y; ps.z += e * uh.z; ps.w += e * uh.w;
        }
        psum[ig][d4 + 0] = ps.x; psum[ig][d4 + 1] = ps.y;
        psum[ig][d4 + 2] = ps.z; psum[ig][d4 + 3] = ps.w;
        __syncthreads();
        if (t < 16) {
            float s = 0.f;
            for (int g = 0; g < 64; ++g) s += psum[g][t];
            s /= sumE;
            float q = s * s;
            q += __shfl_xor(q, 1, 16); q += __shfl_xor(q, 2, 16);
            q += __shfl_xor(q, 4, 16); q += __shfl_xor(q, 8, 16);
            v_s[t] = s * sqrtf(q) / (1.f + q);
        }
        __syncthreads();
        if (iter < 3) {
            const float v0 = v_s[d4 + 0], v1 = v_s[d4 + 1];
            const float v2 = v_s[d4 + 2], v3 = v_s[d4 + 3];
            for (int i = ig; i < 1152; i += 64) {
                const float4 uh = uhat4(ub + i * 8, wo + (size_t)i * 128 + d4);
                float pr = uh.x * v0 + uh.y * v1 + uh.z * v2 + uh.w * v3;
                pr += __shfl_xor(pr, 1, 64);
                pr += __shfl_xor(pr, 2, 64);
                if (dq == 0) logits[i] += pr;
            }
            __syncthreads();
        }
    }
    if (t < 16) out[((size_t)b * 10 + o) * 16 + t] = v_s[t];
}

extern "C" void kernel_launch(void* const* d_in, const int* in_sizes, int n_in,
                              void* d_out, int out_size, void* d_ws, size_t ws_size,
                              hipStream_t stream)
{
    const float* img = (const float*)d_in[0];
    const float* c1w = (const float*)d_in[1];
    const float* c1b = (const float*)d_in[2];
    const float* pw  = (const float*)d_in[3];
    const float* pb  = (const float*)d_in[4];
    const float* rw  = (const float*)d_in[5];
    float* out = (float*)d_out;
    char* ws = (char*)d_ws;
    float* x    = (float*)(ws);                            // 52,428,800 B
    float* part = (float*)(ws + 52428800);                 // 18,874,368 B
    float* u    = (float*)(ws + 52428800 + 18874368);      //  4,718,592 B
    float* wT   = (float*)(ws + 52428800 + 18874368 + 4718592);  // 22,020,096 B

    hipLaunchKernelGGL(wtrans_kernel, dim3((4 * 256 * 81 * 16 + 255) / 256), dim3(256), 0, stream, pw, wT);
    hipLaunchKernelGGL(conv1_kernel, dim3(4, 128), dim3(256), 0, stream, img, c1w, c1b, x);
    hipLaunchKernelGGL(pcaps_kernel, dim3(32, 4, 4), dim3(384), 0, stream, x, wT, part);
    hipLaunchKernelGGL(squash_kernel, dim3(576), dim3(256), 0, stream, part, pb, u);
    hipLaunchKernelGGL(routing_kernel, dim3(128, 10), dim3(256), 0, stream, u, rw, out);
}